// Round 4
// baseline (625.841 us; speedup 1.0000x reference)
//
#include <hip/hip_runtime.h>

// DYConv2d on MI355X — rank-1-factorized dynamic conv via 9 shifted GEMMs.
//   y[b,o,p] = a_oup[b,o] * Sum_k a_k[b,k] * Sum_c W[o,c,k] * (a_inp[b,c]*x[b,c,p+off_k])
// Numerics (adaptive on ws_size; ws_size is constant -> same launch sequence
// every call, graph-capture safe):
//   XLO=1: bf16x3 split (W hi/lo, X hi/lo, drop lo*lo) ~ fp32 (~1e-5 abs)
//   XLO=0: bf16x2 (W hi/lo, X single bf16), err ~1e-4 rms
// X staging is b-chunked: xtp buffer holds CHUNK<=32 samples; {xsplit,conv}
// loop over chunks on the stream (stream order serializes buffer reuse).
//
// Conv roofline (bf16x3): 96 FLOP/staged-byte; 3.83 GB staged / 386 GFLOP per
// pass -> needs 9.1 TB/s staging at 900 TF, served by L2/L3 (W 2.3MB shared,
// per-block X footprint 252KB re-read 36x) -> compute-bound ~430us predicted.
//
// ws layout (bytes):
//   s       @ 0        (32*256 f32)
//   a_inp   @ 32768    (32*256 f32)
//   aoup_s  @ 65536    (32*256 f32)   = sigmoid(..)*a_k[b][8]
//   rho     @ 98304    (32*8   f32)   = a_k[t-1]/a_k[t]  (Horner ratios)
//   wt_hi   @ 99328    [9][256][256] bf16 (c-contig)
//   wt_lo   @ +1179648
//   xtp_hi  @ 2458624  [CHUNK][3456][256] bf16 (padded-58 image, a_inp folded)
//   xtp_lo  @ xtp_hi + CHUNK*1769472   (XLO=1 only)

typedef __attribute__((ext_vector_type(8))) short s16x8;
typedef __attribute__((ext_vector_type(4))) float fx4;

#define PP_FIRST 59       // first valid padded flat index = (h=0+1)*58 + (w=0+1)
#define XTP_ROWS 3456     // conv reads rows [0, 3445]; rows outside data zeroed

__device__ __forceinline__ unsigned short bf16_rne(float f){
  unsigned u = __builtin_bit_cast(unsigned, f);
  u += 0x7fffu + ((u >> 16) & 1u);
  return (unsigned short)(u >> 16);
}
__device__ __forceinline__ float bf16_to_f(unsigned short h){
  unsigned u = ((unsigned)h) << 16;
  return __builtin_bit_cast(float, u);
}

// ---------- K1: global average pool  s[b*256+c] ----------
__global__ void pool_kernel(const float* __restrict__ x, float* __restrict__ s){
  const int bc = blockIdx.x;                 // 0..8191
  const float* p = x + (size_t)bc * 3136;
  const int t = threadIdx.x;
  float sum = 0.f;
  for(int i = t; i < 784; i += 256){         // 784 float4 = 3136 f32
    float4 v = ((const float4*)p)[i];
    sum += v.x + v.y + v.z + v.w;
  }
  for(int o = 32; o > 0; o >>= 1) sum += __shfl_down(sum, o);
  __shared__ float red[4];
  if((t & 63) == 0) red[t >> 6] = sum;
  __syncthreads();
  if(t == 0) s[bc] = (red[0] + red[1] + red[2] + red[3]) * (1.0f / 3136.0f);
}

// ---------- K2: attention FC chain (tiny; one block) ----------
__global__ void fc_kernel(const float* __restrict__ s,
                          const float* __restrict__ shw, const float* __restrict__ shb,
                          const float* __restrict__ inw, const float* __restrict__ inb,
                          const float* __restrict__ ouw, const float* __restrict__ oub,
                          const float* __restrict__ kw,  const float* __restrict__ kb,
                          float* __restrict__ a_inp, float* __restrict__ aoup_s,
                          float* __restrict__ rho){
  __shared__ float hh[32*16];
  __shared__ float ak[32*9];
  const int t = threadIdx.x;
  // h = relu(s @ shw^T + shb)
  for(int i = t; i < 512; i += 256){
    int b = i >> 4, r = i & 15;
    float acc = shb[r];
    const float* sp = s + b*256; const float* wp = shw + r*256;
    for(int c = 0; c < 256; ++c) acc += sp[c] * wp[c];
    hh[i] = fmaxf(acc, 0.f);
  }
  __syncthreads();
  // a_k
  for(int i = t; i < 288; i += 256){
    int b = i / 9, k = i % 9;
    float acc = kb[k];
    for(int r = 0; r < 16; ++r) acc += hh[b*16+r] * kw[k*16+r];
    ak[i] = 1.f / (1.f + expf(-acc));
  }
  __syncthreads();
  {  // Horner ratios (256 threads = 32b * 8k)
    int b = t >> 3, k = t & 7;
    rho[t] = ak[b*9+k] / ak[b*9+k+1];
  }
  // a_inp
  for(int i = t; i < 8192; i += 256){
    int b = i >> 8, c = i & 255;
    float acc = inb[c];
    for(int r = 0; r < 16; ++r) acc += hh[b*16+r] * inw[c*16+r];
    a_inp[i] = 1.f / (1.f + expf(-acc));
  }
  // a_oup * a_k[8]
  for(int i = t; i < 8192; i += 256){
    int b = i >> 8, o = i & 255;
    float acc = oub[o];
    for(int r = 0; r < 16; ++r) acc += hh[b*16+r] * ouw[o*16+r];
    aoup_s[i] = (1.f / (1.f + expf(-acc))) * ak[b*9+8];
  }
}

// ---------- K3: base_w split -> Wt[k][o][c] hi/lo bf16 ----------
__global__ void wsplit_kernel(const float* __restrict__ bw,
                              unsigned short* __restrict__ wt_hi,
                              unsigned short* __restrict__ wt_lo){
  const int i = blockIdx.x * 256 + threadIdx.x;    // (o,c) 0..65535
  const float* p = bw + (size_t)i * 9;             // base_w[o][c][0..9) contiguous
  const int o = i >> 8, c = i & 255;
  #pragma unroll
  for(int k = 0; k < 9; ++k){
    float v = p[k];
    unsigned short h = bf16_rne(v);
    unsigned short l = bf16_rne(v - bf16_to_f(h));
    size_t idx = ((size_t)k << 16) + ((size_t)o << 8) + c;
    wt_hi[idx] = h; wt_lo[idx] = l;
  }
}

// ---------- K4: zero pad rows of xtp chunk buffer (once per call) ----------
template<int XLO>
__global__ void zpad_kernel(unsigned short* __restrict__ xtp_hi,
                            unsigned short* __restrict__ xtp_lo){
  const int slot = blockIdx.x, r = blockIdx.y;     // grid (CHUNK, 210)
  const int row = (r < 59) ? r : (3305 + (r - 59));
  const size_t off = ((size_t)slot * XTP_ROWS + row) * 256 + threadIdx.x;
  xtp_hi[off] = 0;
  if(XLO) xtp_lo[off] = 0;
}

// ---------- K5: transpose + a_inp scale + bf16 split, padded layout ----------
template<int XLO>
__global__ void xsplit_kernel(const float* __restrict__ x, const float* __restrict__ a_inp,
                              unsigned short* __restrict__ xtp_hi,
                              unsigned short* __restrict__ xtp_lo, int b0){
  // grid (4 c-tiles, 56 h, CH)
  const int c0 = blockIdx.x * 64, h = blockIdx.y;
  const int slot = blockIdx.z, b = b0 + slot;
  __shared__ float tile[64 * 59];                  // [c_local][w], stride 59
  __shared__ float ainp_s[64];
  const int t = threadIdx.x;
  if(t < 64) ainp_s[t] = a_inp[(b << 8) + c0 + t];
  const float* xb = x + ((size_t)b * 256 + c0) * 3136 + h * 56;
  for(int i = t; i < 1792; i += 256){              // 64 rows * 28 float2
    int c = i / 28, w2 = (i % 28) * 2;
    float2 v = *(const float2*)(xb + (size_t)c * 3136 + w2);
    tile[c * 59 + w2]     = v.x;
    tile[c * 59 + w2 + 1] = v.y;
  }
  __syncthreads();
  const size_t base = ((size_t)slot * XTP_ROWS + (size_t)(h + 1) * 58) * 256 + c0;
  for(int i = t; i < 58 * 32; i += 256){           // 58 padded w-slots * 32 c-pairs
    int wp = i >> 5, cp = (i & 31) * 2;
    float v0 = 0.f, v1 = 0.f;
    if(wp >= 1 && wp <= 56){
      v0 = tile[cp * 59 + (wp - 1)] * ainp_s[cp];
      v1 = tile[(cp + 1) * 59 + (wp - 1)] * ainp_s[cp + 1];
    }
    unsigned short h0 = bf16_rne(v0), h1 = bf16_rne(v1);
    size_t idx = base + (size_t)wp * 256 + cp;
    *(unsigned*)(xtp_hi + idx) = (unsigned)h0 | ((unsigned)h1 << 16);
    if(XLO){
      unsigned short l0 = bf16_rne(v0 - bf16_to_f(h0));
      unsigned short l1 = bf16_rne(v1 - bf16_to_f(h1));
      *(unsigned*)(xtp_lo + idx) = (unsigned)l0 | ((unsigned)l1 << 16);
    }
  }
}

// ---------- K6: the conv — 9 shifted GEMMs, Horner over taps ----------
// Block: 256 thr (4 waves, 2x2), tile 128(o) x 128(pp), BK=64.
// LDS: Xhi@0 Whi@16K Wlo@32K [Xlo@48K], each [128 rows][64 c] bf16,
// row-XOR-swizzled ((row&7) on 16B granules); global_load_lds with
// pre-swizzled SOURCE (linear dest) per rule #21.
#define GLDS(gp, lo_) __builtin_amdgcn_global_load_lds( \
    (const __attribute__((address_space(1))) void*)(gp), \
    (__attribute__((address_space(3))) void*)(lds + (lo_)), 16, 0, 0)

template<int XLO>
__launch_bounds__(256, 2)
__global__ void conv_kernel(const unsigned short* __restrict__ wt_hi,
                            const unsigned short* __restrict__ wt_lo,
                            const unsigned short* __restrict__ xtp_hi,
                            const unsigned short* __restrict__ xtp_lo,
                            const float* __restrict__ aoup_s,
                            const float* __restrict__ rho,
                            float* __restrict__ out, int b0){
  __shared__ unsigned char lds[XLO ? 65536 : 49152];
  const int tile = blockIdx.x;            // 0..25
  const int o0   = blockIdx.y << 7;       // 0,128
  const int slot = blockIdx.z;
  const int b    = b0 + slot;
  const int pp0  = PP_FIRST + tile * 128;
  const int t    = threadIdx.x;
  const int lane = t & 63;
  const int wave = t >> 6;
  const int wm = wave >> 1, wn = wave & 1;

  fx4 acc[4][4];
  #pragma unroll
  for(int i = 0; i < 4; ++i)
    #pragma unroll
    for(int j = 0; j < 4; ++j)
      acc[i][j] = fx4{0.f, 0.f, 0.f, 0.f};

  // staging geometry: g = rnd*256+t -> row = g>>3 (64-c row = 128B = 8 granules)
  const int srow = t >> 3;                               // + rnd*32
  const int sg8  = (((t & 7) ^ ((t >> 3) & 7)) << 3);    // pre-swizzled src granule (elems)
  const int ldsu = wave << 10;                           // + rnd*4096 + buffer base

  // compute-side frag addresses (bytes), row-stride 128
  const int rA  = lane & 15;
  const int kg  = lane >> 4;
  const int r7  = rA & 7;
  const int gk0 = ((kg ^ r7) << 4);            // k-step 0
  const int gk1 = (((4 + kg) ^ r7) << 4);      // k-step 1
  const int aRow = ((wm << 6) + rA) * 128;
  const int bRow = ((wn << 6) + rA) * 128;

  const size_t xrow0 = (size_t)slot * XTP_ROWS * 256;

  for(int tap = 0; tap < 9; ++tap){
    if(tap > 0){
      const float rr = rho[(b << 3) + tap - 1];
      #pragma unroll
      for(int i = 0; i < 4; ++i)
        #pragma unroll
        for(int j = 0; j < 4; ++j)
          #pragma unroll
          for(int r = 0; r < 4; ++r) acc[i][j][r] *= rr;
    }
    const int off = (tap / 3 - 1) * 58 + (tap % 3 - 1);  // padded-space shift
    const unsigned short* xh0 = xtp_hi + xrow0 + (size_t)(pp0 + off + srow) * 256 + sg8;
    const unsigned short* xl0 = XLO ? (xtp_lo + xrow0 + (size_t)(pp0 + off + srow) * 256 + sg8) : xh0;
    const unsigned short* wh0 = wt_hi + ((size_t)(tap * 256 + o0 + srow)) * 256 + sg8;
    const unsigned short* wl0 = wt_lo + ((size_t)(tap * 256 + o0 + srow)) * 256 + sg8;

    for(int cc = 0; cc < 4; ++cc){
      const int co = cc << 6;
      #pragma unroll
      for(int rnd = 0; rnd < 4; ++rnd){
        GLDS(xh0 + co + rnd * 8192,     0 + rnd * 4096 + ldsu);
        GLDS(wh0 + co + rnd * 8192, 16384 + rnd * 4096 + ldsu);
        GLDS(wl0 + co + rnd * 8192, 32768 + rnd * 4096 + ldsu);
        if(XLO) GLDS(xl0 + co + rnd * 8192, 49152 + rnd * 4096 + ldsu);
      }
      __syncthreads();   // compiler drains vmcnt before s_barrier -> staged data visible
      #pragma unroll
      for(int ks = 0; ks < 2; ++ks){
        const int gk = ks ? gk1 : gk0;
        s16x8 ah[4], al[4], bh[4], bl[4];
        #pragma unroll
        for(int i = 0; i < 4; ++i){
          const int ro = aRow + i * 2048 + gk;
          ah[i] = *(const s16x8*)(lds + 16384 + ro);
          al[i] = *(const s16x8*)(lds + 32768 + ro);
        }
        #pragma unroll
        for(int j = 0; j < 4; ++j){
          const int ro = bRow + j * 2048 + gk;
          bh[j] = *(const s16x8*)(lds + ro);
          if(XLO) bl[j] = *(const s16x8*)(lds + 49152 + ro);
        }
        #pragma unroll
        for(int i = 0; i < 4; ++i)
          #pragma unroll
          for(int j = 0; j < 4; ++j){
            acc[i][j] = __builtin_amdgcn_mfma_f32_16x16x32_bf16(ah[i], bh[j], acc[i][j], 0, 0, 0);
            acc[i][j] = __builtin_amdgcn_mfma_f32_16x16x32_bf16(al[i], bh[j], acc[i][j], 0, 0, 0);
            if(XLO)
              acc[i][j] = __builtin_amdgcn_mfma_f32_16x16x32_bf16(ah[i], bl[j], acc[i][j], 0, 0, 0);
          }
      }
      __syncthreads();   // compute done before next stage overwrites
    }
  }

  // epilogue: * a_oup[b,o]*a_k[b,8]; map padded pp -> (h,w); drop pad cols/rows
  float sc[4][4];
  #pragma unroll
  for(int i = 0; i < 4; ++i){
    const int ob = o0 + (wm << 6) + i * 16 + (kg << 2);
    #pragma unroll
    for(int r = 0; r < 4; ++r) sc[i][r] = aoup_s[(b << 8) + ob + r];
  }
  #pragma unroll
  for(int j = 0; j < 4; ++j){
    const int pp = pp0 + (wn << 6) + j * 16 + rA;
    const int hp = pp / 58, wp = pp % 58;
    if(hp >= 1 && hp <= 56 && wp >= 1 && wp <= 56){
      const int p = (hp - 1) * 56 + (wp - 1);
      #pragma unroll
      for(int i = 0; i < 4; ++i){
        const int ob = o0 + (wm << 6) + i * 16 + (kg << 2);
        float* op = out + ((size_t)((b << 8) + ob)) * 3136 + p;
        #pragma unroll
        for(int r = 0; r < 4; ++r) op[(size_t)r * 3136] = acc[i][j][r] * sc[i][r];
      }
    }
  }
}

extern "C" void kernel_launch(void* const* d_in, const int* in_sizes, int n_in,
                              void* d_out, int out_size, void* d_ws, size_t ws_size,
                              hipStream_t stream){
  const float* x   = (const float*)d_in[0];
  const float* bw  = (const float*)d_in[1];
  const float* shw = (const float*)d_in[2];
  const float* shb = (const float*)d_in[3];
  const float* inw = (const float*)d_in[4];
  const float* inb = (const float*)d_in[5];
  const float* ouw = (const float*)d_in[6];
  const float* oub = (const float*)d_in[7];
  const float* kw  = (const float*)d_in[8];
  const float* kb  = (const float*)d_in[9];
  float* out = (float*)d_out;

  char* ws = (char*)d_ws;
  float* s      = (float*)(ws);
  float* a_inp  = (float*)(ws + 32768);
  float* aoup_s = (float*)(ws + 65536);
  float* rho    = (float*)(ws + 98304);
  unsigned short* wt_hi  = (unsigned short*)(ws + 99328);
  unsigned short* wt_lo  = wt_hi + 9 * 256 * 256;
  unsigned short* xtp_hi = (unsigned short*)(ws + 99328 + (size_t)2 * 9 * 256 * 256 * 2);

  // workspace policy (ws_size constant per process -> fixed launch sequence)
  const size_t FIXED = 2458624;                    // header + wt hi/lo
  const size_t PERB1 = (size_t)XTP_ROWS * 256 * 2; // 1,769,472 per sample per copy
  const size_t avail = ws_size > FIXED ? ws_size - FIXED : 0;
  size_t c3 = avail / (2 * PERB1); if(c3 > 32) c3 = 32;
  size_t c1 = avail / PERB1;       if(c1 > 32) c1 = 32;
  int xlo, CH;
  if(c3 == 32)     { xlo = 1; CH = 32; }
  else if(c1 == 32){ xlo = 0; CH = 32; }
  else if(c3 >= 8) { xlo = 1; CH = (int)c3; }
  else if(c1 >= 1) { xlo = 0; CH = (int)c1; }
  else             { xlo = 0; CH = 1; }            // nothing fits; best effort
  unsigned short* xtp_lo = xtp_hi + (size_t)CH * XTP_ROWS * 256;  // XLO=1 only

  hipLaunchKernelGGL(pool_kernel,   dim3(8192), dim3(256), 0, stream, x, s);
  hipLaunchKernelGGL(fc_kernel,     dim3(1),    dim3(256), 0, stream,
                     s, shw, shb, inw, inb, ouw, oub, kw, kb, a_inp, aoup_s, rho);
  hipLaunchKernelGGL(wsplit_kernel, dim3(256),  dim3(256), 0, stream, bw, wt_hi, wt_lo);

  if(xlo){
    hipLaunchKernelGGL(zpad_kernel<1>, dim3(CH, 210), dim3(256), 0, stream, xtp_hi, xtp_lo);
    for(int b0 = 0; b0 < 32; b0 += CH){
      const int z = (32 - b0 < CH) ? (32 - b0) : CH;
      hipLaunchKernelGGL(xsplit_kernel<1>, dim3(4, 56, z), dim3(256), 0, stream,
                         x, a_inp, xtp_hi, xtp_lo, b0);
      hipLaunchKernelGGL(conv_kernel<1>,   dim3(26, 2, z), dim3(256), 0, stream,
                         wt_hi, wt_lo, xtp_hi, xtp_lo, aoup_s, rho, out, b0);
    }
  } else {
    hipLaunchKernelGGL(zpad_kernel<0>, dim3(CH, 210), dim3(256), 0, stream, xtp_hi, xtp_hi);
    for(int b0 = 0; b0 < 32; b0 += CH){
      const int z = (32 - b0 < CH) ? (32 - b0) : CH;
      hipLaunchKernelGGL(xsplit_kernel<0>, dim3(4, 56, z), dim3(256), 0, stream,
                         x, a_inp, xtp_hi, xtp_hi, b0);
      hipLaunchKernelGGL(conv_kernel<0>,   dim3(26, 2, z), dim3(256), 0, stream,
                         wt_hi, wt_lo, xtp_hi, xtp_hi, aoup_s, rho, out, b0);
    }
  }
}

// Round 6
// 484.926 us; speedup vs baseline: 1.2906x; 1.2906x over previous
//
#include <hip/hip_runtime.h>

// DYConv2d on MI355X — rank-1-factorized dynamic conv via 9 shifted GEMMs.
//   y[b,o,p] = a_oup[b,o] * Sum_k a_k[b,k] * Sum_c W[o,c,k] * (a_inp[b,c]*x[b,c,p+off_k])
// R6 = R5 resubmitted unchanged (infra failure; kernel never ran; desk audit clean).
// R5: bf16x2 (W hi/lo, X hi), sorted-Horner (taps ascending a_k, ratios<=1),
//     tile 128(o) x 256(pp) — staged bytes 3.99->1.96 GB, MFMA 377->251 GFLOP.
// R4 baseline: conv 363us MfmaUtil 47.6% (staging-BW-bound), total 626us,
//     absmax 3.9e-3 (Horner amplification — fixed here by sorting).
//
// ws layout (bytes):
//   s       @ 0        (32*256 f32)
//   a_inp   @ 32768    (32*256 f32)
//   aoup_s  @ 65536    (32*256 f32)  = sigmoid(..)*max_k a_k
//   rho     @ 98304    (32*8 f32)    = sorted ratios a_k[t]/a_k[t+1] <= 1
//   tpk     @ 99328    (32*32 int)   = per-b {kernel-tap, padded-offset} pairs
//   wt_hi   @ 103424   [9][256][256] bf16 (c-contig)
//   wt_lo   @ 1283072  [9][256][256] bf16
//   xtp     @ 2462720  [CH][3456][256] bf16 (padded-58 image, a_inp folded)

typedef __attribute__((ext_vector_type(8))) short s16x8;
typedef __attribute__((ext_vector_type(4))) float fx4;

#define PP_FIRST 59       // first valid padded flat index = (h=0+1)*58 + (w=0+1)
#define XTP_ROWS 3456     // conv reads rows [0,3445]; rows outside data zeroed

__device__ __forceinline__ unsigned short bf16_rne(float f){
  unsigned u = __builtin_bit_cast(unsigned, f);
  u += 0x7fffu + ((u >> 16) & 1u);
  return (unsigned short)(u >> 16);
}
__device__ __forceinline__ float bf16_to_f(unsigned short h){
  unsigned u = ((unsigned)h) << 16;
  return __builtin_bit_cast(float, u);
}

// ---------- K1: global average pool  s[b*256+c] ----------
__global__ void pool_kernel(const float* __restrict__ x, float* __restrict__ s){
  const int bc = blockIdx.x;                 // 0..8191
  const float* p = x + (size_t)bc * 3136;
  const int t = threadIdx.x;
  float sum = 0.f;
  for(int i = t; i < 784; i += 256){
    float4 v = ((const float4*)p)[i];
    sum += v.x + v.y + v.z + v.w;
  }
  for(int o = 32; o > 0; o >>= 1) sum += __shfl_down(sum, o);
  __shared__ float red[4];
  if((t & 63) == 0) red[t >> 6] = sum;
  __syncthreads();
  if(t == 0) s[bc] = (red[0] + red[1] + red[2] + red[3]) * (1.0f / 3136.0f);
}

// ---------- K2: attention FC chain + per-b tap sort (one block) ----------
__global__ void fc_kernel(const float* __restrict__ s,
                          const float* __restrict__ shw, const float* __restrict__ shb,
                          const float* __restrict__ inw, const float* __restrict__ inb,
                          const float* __restrict__ ouw, const float* __restrict__ oub,
                          const float* __restrict__ kw,  const float* __restrict__ kb,
                          float* __restrict__ a_inp, float* __restrict__ aoup_s,
                          float* __restrict__ rho, int* __restrict__ tpk){
  __shared__ float hh[32*16];
  __shared__ float ak[32*9];
  __shared__ float akmax[32];
  const int t = threadIdx.x;
  // h = relu(s @ shw^T + shb)
  for(int i = t; i < 512; i += 256){
    int b = i >> 4, r = i & 15;
    float acc = shb[r];
    const float* sp = s + b*256; const float* wp = shw + r*256;
    for(int c = 0; c < 256; ++c) acc += sp[c] * wp[c];
    hh[i] = fmaxf(acc, 0.f);
  }
  __syncthreads();
  // a_k
  for(int i = t; i < 288; i += 256){
    int b = i / 9, k = i % 9;
    float acc = kb[k];
    for(int r = 0; r < 16; ++r) acc += hh[b*16+r] * kw[k*16+r];
    ak[i] = 1.f / (1.f + expf(-acc));
  }
  __syncthreads();
  // sort taps ascending by a_k -> rescale ratios <= 1 (no error amplification)
  if(t < 32){
    float v[9]; int id[9];
    for(int j = 0; j < 9; ++j){ v[j] = ak[t*9 + j]; id[j] = j; }
    for(int a = 1; a < 9; ++a){
      float vv = v[a]; int ii = id[a]; int p = a - 1;
      while(p >= 0 && v[p] > vv){ v[p+1] = v[p]; id[p+1] = id[p]; --p; }
      v[p+1] = vv; id[p+1] = ii;
    }
    for(int j = 0; j < 9; ++j){
      tpk[t*32 + 2*j]     = id[j];                              // kernel tap index
      tpk[t*32 + 2*j + 1] = (id[j]/3 - 1)*58 + (id[j]%3 - 1);   // padded shift
    }
    for(int j = 0; j < 8; ++j) rho[t*8 + j] = v[j] / v[j+1];    // <= 1
    akmax[t] = v[8];
  }
  __syncthreads();
  // a_inp
  for(int i = t; i < 8192; i += 256){
    int b = i >> 8, c = i & 255;
    float acc = inb[c];
    for(int r = 0; r < 16; ++r) acc += hh[b*16+r] * inw[c*16+r];
    a_inp[i] = 1.f / (1.f + expf(-acc));
  }
  // a_oup * max a_k
  for(int i = t; i < 8192; i += 256){
    int b = i >> 8, o = i & 255;
    float acc = oub[o];
    for(int r = 0; r < 16; ++r) acc += hh[b*16+r] * ouw[o*16+r];
    aoup_s[i] = (1.f / (1.f + expf(-acc))) * akmax[b];
  }
}

// ---------- K3: base_w split -> Wt[k][o][c] hi/lo bf16 ----------
__global__ void wsplit_kernel(const float* __restrict__ bw,
                              unsigned short* __restrict__ wt_hi,
                              unsigned short* __restrict__ wt_lo){
  const int i = blockIdx.x * 256 + threadIdx.x;    // (o,c) 0..65535
  const float* p = bw + (size_t)i * 9;
  const int o = i >> 8, c = i & 255;
  #pragma unroll
  for(int k = 0; k < 9; ++k){
    float v = p[k];
    unsigned short h = bf16_rne(v);
    unsigned short l = bf16_rne(v - bf16_to_f(h));
    size_t idx = ((size_t)k << 16) + ((size_t)o << 8) + c;
    wt_hi[idx] = h; wt_lo[idx] = l;
  }
}

// ---------- K4: zero pad rows of xtp chunk buffer ----------
__global__ void zpad_kernel(unsigned short* __restrict__ xtp){
  const int slot = blockIdx.x, r = blockIdx.y;     // grid (CH, 210)
  const int row = (r < 59) ? r : (3305 + (r - 59));
  xtp[((size_t)slot * XTP_ROWS + row) * 256 + threadIdx.x] = 0;
}

// ---------- K5: transpose + a_inp scale + bf16 cast, padded layout ----------
__global__ void xsplit_kernel(const float* __restrict__ x, const float* __restrict__ a_inp,
                              unsigned short* __restrict__ xtp, int b0){
  const int c0 = blockIdx.x * 64, h = blockIdx.y;  // grid (4, 56, CH)
  const int slot = blockIdx.z, b = b0 + slot;
  __shared__ float tile[64 * 59];
  __shared__ float ainp_s[64];
  const int t = threadIdx.x;
  if(t < 64) ainp_s[t] = a_inp[(b << 8) + c0 + t];
  const float* xb = x + ((size_t)b * 256 + c0) * 3136 + h * 56;
  for(int i = t; i < 1792; i += 256){
    int c = i / 28, w2 = (i % 28) * 2;
    float2 v = *(const float2*)(xb + (size_t)c * 3136 + w2);
    tile[c * 59 + w2]     = v.x;
    tile[c * 59 + w2 + 1] = v.y;
  }
  __syncthreads();
  const size_t base = ((size_t)slot * XTP_ROWS + (size_t)(h + 1) * 58) * 256 + c0;
  for(int i = t; i < 58 * 32; i += 256){
    int wp = i >> 5, cp = (i & 31) * 2;
    float v0 = 0.f, v1 = 0.f;
    if(wp >= 1 && wp <= 56){
      v0 = tile[cp * 59 + (wp - 1)] * ainp_s[cp];
      v1 = tile[(cp + 1) * 59 + (wp - 1)] * ainp_s[cp + 1];
    }
    unsigned short h0 = bf16_rne(v0), h1 = bf16_rne(v1);
    *(unsigned*)(xtp + base + (size_t)wp * 256 + cp) = (unsigned)h0 | ((unsigned)h1 << 16);
  }
}

// ---------- K6: conv — 9 sorted shifted GEMMs, tile 128o x 256pp ----------
// 256 thr (4 waves 2x2: 64o x 128pp each, acc 4x8), BK=64 (4 cc-steps of c).
// LDS 64KB: X@0 (256 rows x 64c), Whi@32K, Wlo@48K (128 rows x 64c each);
// rows XOR-swizzled ((row&7) on 16B granules), global_load_lds linear dest
// + pre-swizzled global source (rule #21). 2 blocks/CU.
#define GLDS(gp, lo_) __builtin_amdgcn_global_load_lds( \
    (const __attribute__((address_space(1))) void*)(gp), \
    (__attribute__((address_space(3))) void*)(lds + (lo_)), 16, 0, 0)

__launch_bounds__(256, 2)
__global__ void conv_kernel(const unsigned short* __restrict__ wt_hi,
                            const unsigned short* __restrict__ wt_lo,
                            const unsigned short* __restrict__ xtp,
                            const float* __restrict__ aoup_s,
                            const float* __restrict__ rho,
                            const int* __restrict__ tpk,
                            float* __restrict__ out, int b0){
  __shared__ unsigned char lds[65536];
  const int tile = blockIdx.x;            // 0..12
  const int o0   = blockIdx.y << 7;       // 0,128
  const int slot = blockIdx.z;
  const int b    = b0 + slot;
  const int pp0  = PP_FIRST + tile * 256;
  const int t    = threadIdx.x;
  const int lane = t & 63;
  const int wave = t >> 6;
  const int wm = wave >> 1, wn = wave & 1;

  fx4 acc[4][8];
  #pragma unroll
  for(int i = 0; i < 4; ++i)
    #pragma unroll
    for(int j = 0; j < 8; ++j)
      acc[i][j] = fx4{0.f, 0.f, 0.f, 0.f};

  // staging geometry: g = rnd*256+t -> row = g>>3 (64-c row = 128B = 8 granules)
  const int srow = t >> 3;                               // + rnd*32
  const int sg8  = (((t & 7) ^ ((t >> 3) & 7)) << 3);    // pre-swizzled src granule
  const int ldsu = wave << 10;                           // + rnd*4096 + region base

  // compute-side frag addresses (bytes), row-stride 128
  const int rA  = lane & 15;
  const int kg  = lane >> 4;
  const int r7  = rA & 7;
  const int gk0 = ((kg ^ r7) << 4);            // k-step 0
  const int gk1 = (((4 + kg) ^ r7) << 4);      // k-step 1
  const int aRow = ((wm << 6) + rA) * 128;     // W rows (64 per wave)
  const int bRow = ((wn << 7) + rA) * 128;     // X rows (128 per wave)

  const size_t xrow0 = (size_t)slot * XTP_ROWS * 256;

  for(int tap = 0; tap < 9; ++tap){
    if(tap > 0){
      const float rr = rho[(b << 3) + tap - 1];   // <= 1 (sorted)
      #pragma unroll
      for(int i = 0; i < 4; ++i)
        #pragma unroll
        for(int j = 0; j < 8; ++j)
          #pragma unroll
          for(int r = 0; r < 4; ++r) acc[i][j][r] *= rr;
    }
    const int pt  = tpk[(b << 5) + (tap << 1)];      // kernel tap (sorted order)
    const int off = tpk[(b << 5) + (tap << 1) + 1];  // padded-space shift
    const unsigned short* xp  = xtp + xrow0 + (size_t)(pp0 + off + srow) * 256 + sg8;
    const unsigned short* wh0 = wt_hi + ((size_t)(pt * 256 + o0 + srow)) * 256 + sg8;
    const unsigned short* wl0 = wt_lo + ((size_t)(pt * 256 + o0 + srow)) * 256 + sg8;

    for(int cc = 0; cc < 4; ++cc){
      const int co = cc << 6;
      #pragma unroll
      for(int rnd = 0; rnd < 8; ++rnd)            // X: 256 rows
        GLDS(xp + co + rnd * 8192, 0 + rnd * 4096 + ldsu);
      #pragma unroll
      for(int rnd = 0; rnd < 4; ++rnd){           // W hi/lo: 128 rows each
        GLDS(wh0 + co + rnd * 8192, 32768 + rnd * 4096 + ldsu);
        GLDS(wl0 + co + rnd * 8192, 49152 + rnd * 4096 + ldsu);
      }
      __syncthreads();   // vmcnt drained before barrier -> staged data visible
      #pragma unroll
      for(int ks = 0; ks < 2; ++ks){
        const int gk = ks ? gk1 : gk0;
        s16x8 ah[4], al[4], bh[8];
        #pragma unroll
        for(int i = 0; i < 4; ++i){
          const int ro = aRow + i * 2048 + gk;
          ah[i] = *(const s16x8*)(lds + 32768 + ro);
          al[i] = *(const s16x8*)(lds + 49152 + ro);
        }
        #pragma unroll
        for(int j = 0; j < 8; ++j)
          bh[j] = *(const s16x8*)(lds + bRow + j * 2048 + gk);
        #pragma unroll
        for(int i = 0; i < 4; ++i)
          #pragma unroll
          for(int j = 0; j < 8; ++j){
            acc[i][j] = __builtin_amdgcn_mfma_f32_16x16x32_bf16(ah[i], bh[j], acc[i][j], 0, 0, 0);
            acc[i][j] = __builtin_amdgcn_mfma_f32_16x16x32_bf16(al[i], bh[j], acc[i][j], 0, 0, 0);
          }
      }
      __syncthreads();   // compute done before next stage overwrites
    }
  }

  // epilogue: * a_oup[b,o]*max_ak; map padded pp -> (h,w); drop pad rows/cols
  float sc[4][4];
  #pragma unroll
  for(int i = 0; i < 4; ++i){
    const int ob = o0 + (wm << 6) + i * 16 + (kg << 2);
    #pragma unroll
    for(int r = 0; r < 4; ++r) sc[i][r] = aoup_s[(b << 8) + ob + r];
  }
  #pragma unroll
  for(int j = 0; j < 8; ++j){
    const int pp = pp0 + (wn << 7) + j * 16 + rA;
    const int hp = pp / 58, wp = pp % 58;
    if(hp >= 1 && hp <= 56 && wp >= 1 && wp <= 56){
      const int p = (hp - 1) * 56 + (wp - 1);
      #pragma unroll
      for(int i = 0; i < 4; ++i){
        const int ob = o0 + (wm << 6) + i * 16 + (kg << 2);
        float* op = out + ((size_t)((b << 8) + ob)) * 3136 + p;
        #pragma unroll
        for(int r = 0; r < 4; ++r) op[(size_t)r * 3136] = acc[i][j][r] * sc[i][r];
      }
    }
  }
}

extern "C" void kernel_launch(void* const* d_in, const int* in_sizes, int n_in,
                              void* d_out, int out_size, void* d_ws, size_t ws_size,
                              hipStream_t stream){
  const float* x   = (const float*)d_in[0];
  const float* bw  = (const float*)d_in[1];
  const float* shw = (const float*)d_in[2];
  const float* shb = (const float*)d_in[3];
  const float* inw = (const float*)d_in[4];
  const float* inb = (const float*)d_in[5];
  const float* ouw = (const float*)d_in[6];
  const float* oub = (const float*)d_in[7];
  const float* kw  = (const float*)d_in[8];
  const float* kb  = (const float*)d_in[9];
  float* out = (float*)d_out;

  char* ws = (char*)d_ws;
  float* s      = (float*)(ws);
  float* a_inp  = (float*)(ws + 32768);
  float* aoup_s = (float*)(ws + 65536);
  float* rho    = (float*)(ws + 98304);
  int*   tpk    = (int*)(ws + 99328);
  unsigned short* wt_hi = (unsigned short*)(ws + 103424);
  unsigned short* wt_lo = wt_hi + 9 * 256 * 256;
  unsigned short* xtp   = (unsigned short*)(ws + 2462720);

  // chunk policy (ws_size constant per process -> fixed launch sequence).
  // R4 ran the 115.7MB path, so ws >= 115.7MB and CH=32 here; fallback kept.
  const size_t FIXED = 2462720;
  const size_t PERB  = (size_t)XTP_ROWS * 256 * 2;   // 1,769,472 B per sample
  const size_t avail = ws_size > FIXED ? ws_size - FIXED : 0;
  size_t chs = avail / PERB; if(chs > 32) chs = 32; if(chs < 1) chs = 1;
  const int CH = (int)chs;

  hipLaunchKernelGGL(pool_kernel,   dim3(8192), dim3(256), 0, stream, x, s);
  hipLaunchKernelGGL(fc_kernel,     dim3(1),    dim3(256), 0, stream,
                     s, shw, shb, inw, inb, ouw, oub, kw, kb, a_inp, aoup_s, rho, tpk);
  hipLaunchKernelGGL(wsplit_kernel, dim3(256),  dim3(256), 0, stream, bw, wt_hi, wt_lo);
  hipLaunchKernelGGL(zpad_kernel,   dim3(CH, 210), dim3(256), 0, stream, xtp);
  for(int b0 = 0; b0 < 32; b0 += CH){
    const int z = (32 - b0 < CH) ? (32 - b0) : CH;
    hipLaunchKernelGGL(xsplit_kernel, dim3(4, 56, z), dim3(256), 0, stream, x, a_inp, xtp, b0);
    hipLaunchKernelGGL(conv_kernel,   dim3(13, 2, z), dim3(256), 0, stream,
                       wt_hi, wt_lo, xtp, aoup_s, rho, tpk, out, b0);
  }
}